// Round 11
// baseline (1251.954 us; speedup 1.0000x reference)
//
#include <hip/hip_runtime.h>
#include <hip/hip_bf16.h>
#include <stdint.h>

typedef __attribute__((ext_vector_type(8))) _Float16 half8;
typedef __attribute__((ext_vector_type(4))) float f32x4;
typedef __attribute__((ext_vector_type(16))) float f32x16;

#define N_TOK  65536
#define DIM    256
#define NT     76          // 32-cluster tiles: 69 (L0) + 6 (L1) + 1 (L2)
#define TAU    0.12f
#define MAXFL  8192        // per-layer flag cap

// padded layer map: L0 tiles [0,69) base 0 size 2197
//                   L1 tiles [69,75) base 2208 size 169
//                   L2 tile  75 base 2400 size 13

// workspace layout (bytes):
// 0       : int cnt[3] (per-layer flag counters)
// 64      : flag lists, 3 layers x 8192 int  (WS_FLAGS(L))
// 98368   : wnorm, 2432 floats (padded index)
// 131072  : fp16 hi W-frags, 76 tiles * 16KB
#define WS_FLAGS(L) (64 + (L) * 32768)
#define WS_WNORM    98368
#define WS_WHFRAG   131072

// -------- prep: pack W into 32x32x16 MFMA A-frag order (fp16 hi) + fp64 wnorm --
__global__ void prep_kernel(const float* __restrict__ w0, const float* __restrict__ w1,
                            const float* __restrict__ w2, unsigned char* __restrict__ ws) {
  const int t = blockIdx.x;
  const int tid = threadIdx.x;           // 256 threads
  const float* wsrc; int basePad, csize;
  if (t < 69)      { wsrc = w0; basePad = 0;    csize = 2197; }
  else if (t < 75) { wsrc = w1; basePad = 2208; csize = 169;  }
  else             { wsrc = w2; basePad = 2400; csize = 13;   }
  half8* whf = (half8*)(ws + WS_WHFRAG);
#pragma unroll
  for (int r = 0; r < 4; ++r) {
    int q = r * 256 + tid;               // frag slot within tile
    int l = q & 63;
    int s = q >> 6;                      // 0..15
    int cit = l & 31;
    int k = s * 16 + (l >> 5) * 8;
    int cl = t * 32 + cit - basePad;
    float xs[8];
    if (cl < csize) {
      const float4* p = (const float4*)(wsrc + (size_t)cl * DIM + k);
      float4 a = p[0], b = p[1];
      xs[0]=a.x; xs[1]=a.y; xs[2]=a.z; xs[3]=a.w; xs[4]=b.x; xs[5]=b.y; xs[6]=b.z; xs[7]=b.w;
    } else {
#pragma unroll
      for (int j = 0; j < 8; ++j) xs[j] = 0.0f;
    }
    half8 h;
#pragma unroll
    for (int j = 0; j < 8; ++j) h[j] = (_Float16)xs[j];
    whf[(size_t)t * 1024 + q] = h;
  }
  // wnorm: 8 threads per cluster, fp64, shuffle-reduce
  {
    int gid = tid >> 3, j = tid & 7;     // gid 0..31
    int cl = t * 32 + gid - basePad;
    double acc = 0.0;
    if (cl >= 0 && cl < csize) {
      const float* row = wsrc + (size_t)cl * DIM + j * 32;
#pragma unroll
      for (int k = 0; k < 32; ++k) { double x = row[k]; acc += x * x; }
    }
    acc += __shfl_xor(acc, 1, 64);
    acc += __shfl_xor(acc, 2, 64);
    acc += __shfl_xor(acc, 4, 64);
    if (j == 0) {
      float* wn = (float*)(ws + WS_WNORM);
      wn[t * 32 + gid] = (cl >= 0 && cl < csize) ? (float)acc : __builtin_inff();
    }
  }
  if (t == 0 && tid < 3) ((int*)ws)[tid] = 0;
}

// -------- main: 64 tok/wave (2 MFMA B-groups), barrier-free A/B streaming -----
__global__ __launch_bounds__(128, 1) void argmin_kernel(
    const float* __restrict__ E, const float* __restrict__ w0, const float* __restrict__ w1,
    const float* __restrict__ w2, float* __restrict__ out, unsigned char* __restrict__ ws) {
  const int tid   = threadIdx.x;
  const int lane  = tid & 63;
  const int wave  = tid >> 6;    // 0..1
  const int col   = lane & 31;   // token within 32-tile
  const int khalf = lane >> 5;   // 0/1 (k sub-block / C-row offset)
  const int tokA  = blockIdx.x * 128 + wave * 64;   // group A token base
  const int tokB  = tokA + 32;                      // group B token base

  // E fragments (B-operand): lane holds E[tok=base+col][k = s*16 + khalf*8 + j]
  half8 ehA[16], ehB[16];
#pragma unroll
  for (int s = 0; s < 16; ++s) {
    {
      const float4* p = (const float4*)(E + (size_t)(tokA + col) * DIM + s * 16 + khalf * 8);
      float4 a = p[0], b = p[1];
      float xs[8] = {a.x, a.y, a.z, a.w, b.x, b.y, b.z, b.w};
      half8 h;
#pragma unroll
      for (int j = 0; j < 8; ++j) h[j] = (_Float16)xs[j];
      ehA[s] = h;
    }
    {
      const float4* p = (const float4*)(E + (size_t)(tokB + col) * DIM + s * 16 + khalf * 8);
      float4 a = p[0], b = p[1];
      float xs[8] = {a.x, a.y, a.z, a.w, b.x, b.y, b.z, b.w};
      half8 h;
#pragma unroll
      for (int j = 0; j < 8; ++j) h[j] = (_Float16)xs[j];
      ehB[s] = h;
    }
  }

  const half8* whf = (const half8*)(ws + WS_WHFRAG);
  const float* wn  = (const float*)(ws + WS_WNORM);

  float v1A = __builtin_inff(), v2A = __builtin_inff();
  float v1B = __builtin_inff(), v2B = __builtin_inff();
  int   i1A = 0x7fffffff, i1B = 0x7fffffff;

#define LOADW(DST, T) { const half8* p_ = whf + (size_t)(T) * 1024; _Pragma("unroll") \
    for (int s = 0; s < 16; ++s) DST[s] = p_[s * 64 + lane]; }

  // two independent MFMA chains (groups A/B share W frags) + fused epilogue
#define TILE(REGS, T)                                                        \
  {                                                                          \
    f32x16 aA = (f32x16){0.f,0.f,0.f,0.f,0.f,0.f,0.f,0.f,                    \
                         0.f,0.f,0.f,0.f,0.f,0.f,0.f,0.f};                   \
    f32x16 aB = aA;                                                          \
    _Pragma("unroll")                                                        \
    for (int s = 0; s < 16; ++s) {                                           \
      aA = __builtin_amdgcn_mfma_f32_32x32x16_f16(REGS[s], ehA[s], aA, 0, 0, 0); \
      aB = __builtin_amdgcn_mfma_f32_32x32x16_f16(REGS[s], ehB[s], aB, 0, 0, 0); \
    }                                                                        \
    _Pragma("unroll")                                                        \
    for (int q = 0; q < 4; ++q) {                                            \
      float4 w4 = *(const float4*)(wn + (T) * 32 + q * 8 + khalf * 4);       \
      float wv[4] = {w4.x, w4.y, w4.z, w4.w};                                \
      _Pragma("unroll")                                                      \
      for (int rr = 0; rr < 4; ++rr) {                                       \
        int c = (T) * 32 + rr + 8 * q + 4 * khalf;                           \
        { float d = __builtin_fmaf(-2.0f, aA[q * 4 + rr], wv[rr]);           \
          bool lt = d < v1A; float hi = fmaxf(d, v1A);                       \
          v1A = fminf(d, v1A); v2A = fminf(v2A, hi); i1A = lt ? c : i1A; }   \
        { float d = __builtin_fmaf(-2.0f, aB[q * 4 + rr], wv[rr]);           \
          bool lt = d < v1B; float hi = fmaxf(d, v1B);                       \
          v1B = fminf(d, v1B); v2B = fminf(v2B, hi); i1B = lt ? c : i1B; }   \
      }                                                                      \
    }                                                                        \
  }

  // per-group finalize: khalf merge, near-tie flag (per-layer list), row write
#define FIN1(LVAL, BASEPAD, WLP, V1, V2, I1, TB)                             \
  {                                                                          \
    float o1 = __shfl_xor(V1, 32, 64);                                       \
    int   oi = __shfl_xor(I1, 32, 64);                                       \
    float o2 = __shfl_xor(V2, 32, 64);                                       \
    float a1 = fminf(V1, o1);                                                \
    float a2 = fminf(fmaxf(V1, o1), fminf(V2, o2));                          \
    int   b1 = (o1 < V1) ? oi : I1;                                          \
    int li = b1 - (BASEPAD);                                                 \
    if (khalf == 0 && (a2 - a1 < TAU)) {                                     \
      int pos = atomicAdd((int*)ws + (LVAL), 1);                             \
      if (pos < MAXFL) ((int*)(ws + WS_FLAGS(LVAL)))[pos] = (TB) + col;      \
    }                                                                        \
    _Pragma("unroll 1")                                                      \
    for (int r = 0; r < 32; ++r) {                                           \
      int ir = __shfl(li, r, 64);                                            \
      const f32x4* src = (const f32x4*)((WLP) + (size_t)ir * DIM);           \
      f32x4* dst = (f32x4*)(out + ((size_t)((LVAL) * N_TOK + (TB) + r)) * DIM); \
      __builtin_nontemporal_store(src[lane], &dst[lane]);                    \
    }                                                                        \
    V1 = __builtin_inff(); V2 = __builtin_inff(); I1 = 0x7fffffff;           \
  }

  half8 wA[16], wB[16];
  LOADW(wA, 0);

#pragma unroll 1
  for (int it = 0; it < NT / 2; ++it) {
    const int t0 = 2 * it, t1 = t0 + 1;
    LOADW(wB, t1);
    TILE(wA, t0);
    if (t0 == 68) { FIN1(0, 0, w0, v1A, v2A, i1A, tokA); FIN1(0, 0, w0, v1B, v2B, i1B, tokB); }
    if (t0 == 74) { FIN1(1, 2208, w1, v1A, v2A, i1A, tokA); FIN1(1, 2208, w1, v1B, v2B, i1B, tokB); }
    if (it + 1 < NT / 2) LOADW(wA, t0 + 2);
    TILE(wB, t1);
    if (t1 == 75) { FIN1(2, 2400, w2, v1A, v2A, i1A, tokA); FIN1(2, 2400, w2, v1B, v2B, i1B, tokB); }
  }
#undef LOADW
#undef TILE
#undef FIN1
}

// ------- refine: E in LDS (broadcast), W transient regs, scalar accumulators --
// 8 flags/group. thread = (rr = tid>>2 row-slot 0..63, q = tid&3 dim-quarter).
// E rows staged in LDS with quarter padding (stride 272 floats, quarter at
// q*68) -> 4 distinct banks per read instr, 16-way broadcast. Per p-step one
// W f32x4 is reused across all 8 tokens. ||e||^2 dropped (token-constant).
__global__ __launch_bounds__(256, 2) void refine_kernel(
    const float* __restrict__ E, const float* __restrict__ w0,
    const float* __restrict__ w1, const float* __restrict__ w2,
    float* __restrict__ out, unsigned char* __restrict__ ws) {
  const int tid  = threadIdx.x;
  const int lane = tid & 63;
  const int wave = tid >> 6;
  const int q    = tid & 3;     // dim quarter (lane bits 0-1)
  const int rr   = tid >> 2;    // 0..63 row slot (lane bits 2-5 + wave)
  const int* cnt = (const int*)ws;
  int c0 = cnt[0] < MAXFL ? cnt[0] : MAXFL;
  int c1 = cnt[1] < MAXFL ? cnt[1] : MAXFL;
  int c2 = cnt[2] < MAXFL ? cnt[2] : MAXFL;
  int g0 = (c0 + 7) >> 3, g1 = (c1 + 7) >> 3, g2 = (c2 + 7) >> 3;
  int gtot = g0 + g1 + g2;
  const float* wn = (const float*)(ws + WS_WNORM);

  __shared__ __align__(16) float esh[8 * 272];   // 8 rows, padded quarters
  __shared__ int   toks[8];
  __shared__ float redd[4][8];
  __shared__ int   redi[4][8];
  __shared__ int   winner[8];

  for (int gid = blockIdx.x; gid < gtot; gid += gridDim.x) {
    int L, gi, cl, csize, basePad; const float* WL;
    if (gid < g0)           { L = 0; gi = gid;           cl = c0; WL = w0; csize = 2197; basePad = 0; }
    else if (gid < g0 + g1) { L = 1; gi = gid - g0;      cl = c1; WL = w1; csize = 169;  basePad = 2208; }
    else                    { L = 2; gi = gid - g0 - g1; cl = c2; WL = w2; csize = 13;   basePad = 2400; }
    const int* fl = (const int*)(ws + WS_FLAGS(L)) + gi * 8;
    const int m = (cl - gi * 8 < 8) ? (cl - gi * 8) : 8;
    __syncthreads();                       // protect shared reuse across groups
    if (tid < 8) toks[tid] = fl[(tid < m) ? tid : 0];
    __syncthreads();
    // stage 8 E rows into LDS (padded): dim d -> t*272 + (d>>6)*68 + (d&63)
#pragma unroll
    for (int s0 = 0; s0 < 2; ++s0) {
      int s = s0 * 256 + tid;              // 0..511 = 8 rows x 64 f32x4
      int t = s >> 6, fq = s & 63;
      f32x4 v = *(const f32x4*)(E + (size_t)toks[t] * DIM + fq * 4);
      *(f32x4*)&esh[t * 272 + (fq >> 4) * 68 + (fq & 15) * 4] = v;
    }
    __syncthreads();

    float best[8]; int bidx[8];
#pragma unroll
    for (int t = 0; t < 8; ++t) { best[t] = __builtin_inff(); bidx[t] = 0x7fffffff; }

#pragma unroll 1
    for (int cb = 0; cb < csize; cb += 64) {
      int c = cb + rr;
      bool ok = c < csize;
      const f32x4* row = (const f32x4*)(WL + (size_t)(ok ? c : 0) * DIM + q * 64);
      float dot[8];
#pragma unroll
      for (int t = 0; t < 8; ++t) dot[t] = 0.f;
#pragma unroll
      for (int p = 0; p < 16; ++p) {
        f32x4 wv = row[p];
#pragma unroll
        for (int t = 0; t < 8; ++t) {
          f32x4 ev = *(const f32x4*)&esh[t * 272 + q * 68 + p * 4];
          dot[t] = __builtin_fmaf(wv.x, ev.x, __builtin_fmaf(wv.y, ev.y,
                   __builtin_fmaf(wv.z, ev.z, __builtin_fmaf(wv.w, ev.w, dot[t]))));
        }
      }
#pragma unroll
      for (int t = 0; t < 8; ++t) {
        float dp = dot[t];
        dp += __shfl_xor(dp, 1, 64);       // combine quarters (all 4 q-lanes
        dp += __shfl_xor(dp, 2, 64);       //  end with identical full sums)
        float d = ok ? (wn[basePad + c] - 2.0f * dp) : __builtin_inff();
        bool lt = (d < best[t]) || (d == best[t] && c < bidx[t]);
        best[t] = lt ? d : best[t];
        bidx[t] = lt ? c : bidx[t];
      }
    }
    // reduce across row-slots within wave (lane bits 2..5)
#pragma unroll
    for (int off = 4; off <= 32; off <<= 1) {
#pragma unroll
      for (int t = 0; t < 8; ++t) {
        float od = __shfl_xor(best[t], off, 64);
        int   oi = __shfl_xor(bidx[t], off, 64);
        bool take = (od < best[t]) || (od == best[t] && oi < bidx[t]);
        best[t] = take ? od : best[t];
        bidx[t] = take ? oi : bidx[t];
      }
    }
    if (lane == 0) {
#pragma unroll
      for (int t = 0; t < 8; ++t) { redd[wave][t] = best[t]; redi[wave][t] = bidx[t]; }
    }
    __syncthreads();
    if (tid < 8) {
      float b = redd[0][tid]; int x = redi[0][tid];
#pragma unroll
      for (int w = 1; w < 4; ++w) {
        if (redd[w][tid] < b || (redd[w][tid] == b && redi[w][tid] < x)) { b = redd[w][tid]; x = redi[w][tid]; }
      }
      winner[tid] = x;
    }
    __syncthreads();
    // gather winner rows: thread writes token (tid>>5), dims [(tid&31)*8, +8)
    {
      int wj = tid >> 5, dbase = (tid & 31) * 8;
      if (wj < m) {
        const f32x4* src = (const f32x4*)(WL + (size_t)winner[wj] * DIM + dbase);
        f32x4* dst = (f32x4*)(out + ((size_t)(L * N_TOK + toks[wj])) * DIM + dbase);
        dst[0] = src[0]; dst[1] = src[1];
      }
    }
  }
}

extern "C" void kernel_launch(void* const* d_in, const int* in_sizes, int n_in,
                              void* d_out, int out_size, void* d_ws, size_t ws_size,
                              hipStream_t stream) {
  const float* E  = (const float*)d_in[0];
  const float* w0 = (const float*)d_in[1];
  const float* w1 = (const float*)d_in[2];
  const float* w2 = (const float*)d_in[3];
  float* out = (float*)d_out;
  unsigned char* ws = (unsigned char*)d_ws;

  hipLaunchKernelGGL(prep_kernel,   dim3(NT),  dim3(256), 0, stream, w0, w1, w2, ws);
  hipLaunchKernelGGL(argmin_kernel, dim3(512), dim3(128), 0, stream, E, w0, w1, w2, out, ws);
  hipLaunchKernelGGL(refine_kernel, dim3(512), dim3(256), 0, stream, E, w0, w1, w2, out, ws);
}

// Round 12
// 429.350 us; speedup vs baseline: 2.9159x; 2.9159x over previous
//
#include <hip/hip_runtime.h>
#include <hip/hip_bf16.h>
#include <stdint.h>

typedef __attribute__((ext_vector_type(8))) _Float16 half8;
typedef __attribute__((ext_vector_type(4))) float f32x4;
typedef __attribute__((ext_vector_type(16))) float f32x16;

#define N_TOK  65536
#define DIM    256
#define NT     76          // 32-cluster tiles: 69 (L0) + 6 (L1) + 1 (L2)
#define TAU    0.12f
#define MAXFL  8192        // per-layer flag cap

// padded layer map: L0 tiles [0,69) base 0 size 2197
//                   L1 tiles [69,75) base 2208 size 169
//                   L2 tile  75 base 2400 size 13

// workspace layout (bytes):
// 0       : int cnt[3] (per-layer flag counters)
// 64      : flag lists, 3 layers x 8192 int  (WS_FLAGS(L))
// 98368   : wnorm, 2432 floats (padded index)
// 131072  : fp16 hi W-frags, 76 tiles * 16KB
#define WS_FLAGS(L) (64 + (L) * 32768)
#define WS_WNORM    98368
#define WS_WHFRAG   131072

// -------- prep: pack W into 32x32x16 MFMA A-frag order (fp16 hi) + fp64 wnorm --
__global__ void prep_kernel(const float* __restrict__ w0, const float* __restrict__ w1,
                            const float* __restrict__ w2, unsigned char* __restrict__ ws) {
  const int t = blockIdx.x;
  const int tid = threadIdx.x;           // 256 threads
  const float* wsrc; int basePad, csize;
  if (t < 69)      { wsrc = w0; basePad = 0;    csize = 2197; }
  else if (t < 75) { wsrc = w1; basePad = 2208; csize = 169;  }
  else             { wsrc = w2; basePad = 2400; csize = 13;   }
  half8* whf = (half8*)(ws + WS_WHFRAG);
#pragma unroll
  for (int r = 0; r < 4; ++r) {
    int q = r * 256 + tid;               // frag slot within tile
    int l = q & 63;
    int s = q >> 6;                      // 0..15
    int cit = l & 31;
    int k = s * 16 + (l >> 5) * 8;
    int cl = t * 32 + cit - basePad;
    float xs[8];
    if (cl < csize) {
      const float4* p = (const float4*)(wsrc + (size_t)cl * DIM + k);
      float4 a = p[0], b = p[1];
      xs[0]=a.x; xs[1]=a.y; xs[2]=a.z; xs[3]=a.w; xs[4]=b.x; xs[5]=b.y; xs[6]=b.z; xs[7]=b.w;
    } else {
#pragma unroll
      for (int j = 0; j < 8; ++j) xs[j] = 0.0f;
    }
    half8 h;
#pragma unroll
    for (int j = 0; j < 8; ++j) h[j] = (_Float16)xs[j];
    whf[(size_t)t * 1024 + q] = h;
  }
  // wnorm: 8 threads per cluster, fp64, shuffle-reduce
  {
    int gid = tid >> 3, j = tid & 7;     // gid 0..31
    int cl = t * 32 + gid - basePad;
    double acc = 0.0;
    if (cl >= 0 && cl < csize) {
      const float* row = wsrc + (size_t)cl * DIM + j * 32;
#pragma unroll
      for (int k = 0; k < 32; ++k) { double x = row[k]; acc += x * x; }
    }
    acc += __shfl_xor(acc, 1, 64);
    acc += __shfl_xor(acc, 2, 64);
    acc += __shfl_xor(acc, 4, 64);
    if (j == 0) {
      float* wn = (float*)(ws + WS_WNORM);
      wn[t * 32 + gid] = (cl >= 0 && cl < csize) ? (float)acc : __builtin_inff();
    }
  }
  if (t == 0 && tid < 3) ((int*)ws)[tid] = 0;
}

// -------- main: 64 tok/wave (2 MFMA B-groups), barrier-free A/B streaming -----
__global__ __launch_bounds__(128, 1) void argmin_kernel(
    const float* __restrict__ E, const float* __restrict__ w0, const float* __restrict__ w1,
    const float* __restrict__ w2, float* __restrict__ out, unsigned char* __restrict__ ws) {
  const int tid   = threadIdx.x;
  const int lane  = tid & 63;
  const int wave  = tid >> 6;    // 0..1
  const int col   = lane & 31;   // token within 32-tile
  const int khalf = lane >> 5;   // 0/1 (k sub-block / C-row offset)
  const int tokA  = blockIdx.x * 128 + wave * 64;   // group A token base
  const int tokB  = tokA + 32;                      // group B token base

  // E fragments (B-operand): lane holds E[tok=base+col][k = s*16 + khalf*8 + j]
  half8 ehA[16], ehB[16];
#pragma unroll
  for (int s = 0; s < 16; ++s) {
    {
      const float4* p = (const float4*)(E + (size_t)(tokA + col) * DIM + s * 16 + khalf * 8);
      float4 a = p[0], b = p[1];
      float xs[8] = {a.x, a.y, a.z, a.w, b.x, b.y, b.z, b.w};
      half8 h;
#pragma unroll
      for (int j = 0; j < 8; ++j) h[j] = (_Float16)xs[j];
      ehA[s] = h;
    }
    {
      const float4* p = (const float4*)(E + (size_t)(tokB + col) * DIM + s * 16 + khalf * 8);
      float4 a = p[0], b = p[1];
      float xs[8] = {a.x, a.y, a.z, a.w, b.x, b.y, b.z, b.w};
      half8 h;
#pragma unroll
      for (int j = 0; j < 8; ++j) h[j] = (_Float16)xs[j];
      ehB[s] = h;
    }
  }

  const half8* whf = (const half8*)(ws + WS_WHFRAG);
  const float* wn  = (const float*)(ws + WS_WNORM);

  float v1A = __builtin_inff(), v2A = __builtin_inff();
  float v1B = __builtin_inff(), v2B = __builtin_inff();
  int   i1A = 0x7fffffff, i1B = 0x7fffffff;

#define LOADW(DST, T) { const half8* p_ = whf + (size_t)(T) * 1024; _Pragma("unroll") \
    for (int s = 0; s < 16; ++s) DST[s] = p_[s * 64 + lane]; }

  // two independent MFMA chains (groups A/B share W frags) + fused epilogue
#define TILE(REGS, T)                                                        \
  {                                                                          \
    f32x16 aA = (f32x16){0.f,0.f,0.f,0.f,0.f,0.f,0.f,0.f,                    \
                         0.f,0.f,0.f,0.f,0.f,0.f,0.f,0.f};                   \
    f32x16 aB = aA;                                                          \
    _Pragma("unroll")                                                        \
    for (int s = 0; s < 16; ++s) {                                           \
      aA = __builtin_amdgcn_mfma_f32_32x32x16_f16(REGS[s], ehA[s], aA, 0, 0, 0); \
      aB = __builtin_amdgcn_mfma_f32_32x32x16_f16(REGS[s], ehB[s], aB, 0, 0, 0); \
    }                                                                        \
    _Pragma("unroll")                                                        \
    for (int q = 0; q < 4; ++q) {                                            \
      float4 w4 = *(const float4*)(wn + (T) * 32 + q * 8 + khalf * 4);       \
      float wv[4] = {w4.x, w4.y, w4.z, w4.w};                                \
      _Pragma("unroll")                                                      \
      for (int rr = 0; rr < 4; ++rr) {                                       \
        int c = (T) * 32 + rr + 8 * q + 4 * khalf;                           \
        { float d = __builtin_fmaf(-2.0f, aA[q * 4 + rr], wv[rr]);           \
          bool lt = d < v1A; float hi = fmaxf(d, v1A);                       \
          v1A = fminf(d, v1A); v2A = fminf(v2A, hi); i1A = lt ? c : i1A; }   \
        { float d = __builtin_fmaf(-2.0f, aB[q * 4 + rr], wv[rr]);           \
          bool lt = d < v1B; float hi = fmaxf(d, v1B);                       \
          v1B = fminf(d, v1B); v2B = fminf(v2B, hi); i1B = lt ? c : i1B; }   \
      }                                                                      \
    }                                                                        \
  }

  // per-group finalize: khalf merge, near-tie flag (per-layer list), row write
#define FIN1(LVAL, BASEPAD, WLP, V1, V2, I1, TB)                             \
  {                                                                          \
    float o1 = __shfl_xor(V1, 32, 64);                                       \
    int   oi = __shfl_xor(I1, 32, 64);                                       \
    float o2 = __shfl_xor(V2, 32, 64);                                       \
    float a1 = fminf(V1, o1);                                                \
    float a2 = fminf(fmaxf(V1, o1), fminf(V2, o2));                          \
    int   b1 = (o1 < V1) ? oi : I1;                                          \
    int li = b1 - (BASEPAD);                                                 \
    if (khalf == 0 && (a2 - a1 < TAU)) {                                     \
      int pos = atomicAdd((int*)ws + (LVAL), 1);                             \
      if (pos < MAXFL) ((int*)(ws + WS_FLAGS(LVAL)))[pos] = (TB) + col;      \
    }                                                                        \
    _Pragma("unroll 1")                                                      \
    for (int r = 0; r < 32; ++r) {                                           \
      int ir = __shfl(li, r, 64);                                            \
      const f32x4* src = (const f32x4*)((WLP) + (size_t)ir * DIM);           \
      f32x4* dst = (f32x4*)(out + ((size_t)((LVAL) * N_TOK + (TB) + r)) * DIM); \
      __builtin_nontemporal_store(src[lane], &dst[lane]);                    \
    }                                                                        \
    V1 = __builtin_inff(); V2 = __builtin_inff(); I1 = 0x7fffffff;           \
  }

  half8 wA[16], wB[16];
  LOADW(wA, 0);

#pragma unroll 1
  for (int it = 0; it < NT / 2; ++it) {
    const int t0 = 2 * it, t1 = t0 + 1;
    LOADW(wB, t1);
    TILE(wA, t0);
    if (t0 == 68) { FIN1(0, 0, w0, v1A, v2A, i1A, tokA); FIN1(0, 0, w0, v1B, v2B, i1B, tokB); }
    if (t0 == 74) { FIN1(1, 2208, w1, v1A, v2A, i1A, tokA); FIN1(1, 2208, w1, v1B, v2B, i1B, tokB); }
    if (it + 1 < NT / 2) LOADW(wA, t0 + 2);
    TILE(wB, t1);
    if (t1 == 75) { FIN1(2, 2400, w2, v1A, v2A, i1A, tokA); FIN1(2, 2400, w2, v1B, v2B, i1B, tokB); }
  }
#undef LOADW
#undef TILE
#undef FIN1
}

// ------- refine: one WAVE per 4-flag quad; E in LDS broadcast; tiny live set --
// No __syncthreads (waves independent). Lane l scans rows cb+l and cb+64+l.
// Per k-step: 2 W f32x4 loads + 4 uniform-address LDS broadcasts + 8 vec FMAs
// into 8 NAMED f32x4 accumulators (reset per cb-iter). ||e||^2 dropped
// (token-constant). fp32 dot-form validated R8-R11 (absmax 0).
__device__ __forceinline__ f32x4 vfma4(f32x4 a, f32x4 b, f32x4 c) {
  f32x4 r;
  r.x = __builtin_fmaf(a.x, b.x, c.x);
  r.y = __builtin_fmaf(a.y, b.y, c.y);
  r.z = __builtin_fmaf(a.z, b.z, c.z);
  r.w = __builtin_fmaf(a.w, b.w, c.w);
  return r;
}

__global__ __launch_bounds__(256, 1) void refine_kernel(
    const float* __restrict__ E, const float* __restrict__ w0,
    const float* __restrict__ w1, const float* __restrict__ w2,
    float* __restrict__ out, unsigned char* __restrict__ ws) {
  const int tid  = threadIdx.x;
  const int lane = tid & 63;
  const int wave = tid >> 6;
  const int* cnt = (const int*)ws;
  int c0 = cnt[0] < MAXFL ? cnt[0] : MAXFL;
  int c1 = cnt[1] < MAXFL ? cnt[1] : MAXFL;
  int c2 = cnt[2] < MAXFL ? cnt[2] : MAXFL;
  int q0 = (c0 + 3) >> 2, q1 = (c1 + 3) >> 2, q2 = (c2 + 3) >> 2;
  int qtot = q0 + q1 + q2;
  const float* wn = (const float*)(ws + WS_WNORM);

  __shared__ __align__(16) float esh[4][4][256];   // [wave][flag][dim], 16KB

  const float INF = __builtin_inff();

  for (int qi = blockIdx.x * 4 + wave; qi < qtot; qi += gridDim.x * 4) {
    int L, qb, cl, csize, basePad; const float* WL;
    if (qi < q0)           { L = 0; qb = qi;           cl = c0; WL = w0; csize = 2197; basePad = 0; }
    else if (qi < q0 + q1) { L = 1; qb = qi - q0;      cl = c1; WL = w1; csize = 169;  basePad = 2208; }
    else                   { L = 2; qb = qi - q0 - q1; cl = c2; WL = w2; csize = 13;   basePad = 2400; }
    const int* fl = (const int*)(ws + WS_FLAGS(L));
    int f0 = qb * 4;
    int mv = cl - f0; mv = mv < 4 ? mv : 4;     // 1..4 valid flags
    int tk0 = fl[f0];
    int tk1 = fl[f0 + (mv > 1 ? 1 : 0)];
    int tk2 = fl[f0 + (mv > 2 ? 2 : 0)];
    int tk3 = fl[f0 + (mv > 3 ? 3 : 0)];
    // stage 4 E rows into this wave's LDS slice (same-wave produce/consume,
    // compiler inserts the lgkmcnt; no barrier needed)
    float* es = &esh[wave][0][0];
    *(f32x4*)&es[0 * 256 + lane * 4] = ((const f32x4*)(E + (size_t)tk0 * DIM))[lane];
    *(f32x4*)&es[1 * 256 + lane * 4] = ((const f32x4*)(E + (size_t)tk1 * DIM))[lane];
    *(f32x4*)&es[2 * 256 + lane * 4] = ((const f32x4*)(E + (size_t)tk2 * DIM))[lane];
    *(f32x4*)&es[3 * 256 + lane * 4] = ((const f32x4*)(E + (size_t)tk3 * DIM))[lane];

    float bd0 = INF, bd1 = INF, bd2 = INF, bd3 = INF;
    int   bi0 = 0x7fffffff, bi1 = 0x7fffffff, bi2 = 0x7fffffff, bi3 = 0x7fffffff;

#pragma unroll 1
    for (int cb = 0; cb < csize; cb += 128) {
      const int ca = cb + lane;
      const int cbh = ca + 64;
      const bool oka = ca < csize;
      const bool okb = cbh < csize;
      const f32x4* ra = (const f32x4*)(WL + (size_t)(oka ? ca : 0) * DIM);
      const f32x4* rb = (const f32x4*)(WL + (size_t)(okb ? cbh : 0) * DIM);
      f32x4 z = (f32x4){0.f, 0.f, 0.f, 0.f};
      f32x4 da0 = z, da1 = z, da2 = z, da3 = z;
      f32x4 db0 = z, db1 = z, db2 = z, db3 = z;
#pragma unroll 16
      for (int k = 0; k < 64; ++k) {
        f32x4 wa = ra[k];
        f32x4 wb = rb[k];
        f32x4 e0 = *(const f32x4*)&es[0 * 256 + k * 4];
        f32x4 e1 = *(const f32x4*)&es[1 * 256 + k * 4];
        f32x4 e2 = *(const f32x4*)&es[2 * 256 + k * 4];
        f32x4 e3 = *(const f32x4*)&es[3 * 256 + k * 4];
        da0 = vfma4(wa, e0, da0); da1 = vfma4(wa, e1, da1);
        da2 = vfma4(wa, e2, da2); da3 = vfma4(wa, e3, da3);
        db0 = vfma4(wb, e0, db0); db1 = vfma4(wb, e1, db1);
        db2 = vfma4(wb, e2, db2); db3 = vfma4(wb, e3, db3);
      }
      float wna = oka ? wn[basePad + ca] : INF;
      float wnb = okb ? wn[basePad + cbh] : INF;
#define UPD(BD, BI, ACC, WNV, C, OK)                                         \
      { float s_ = ((ACC).x + (ACC).y) + ((ACC).z + (ACC).w);                \
        float d_ = (OK) ? __builtin_fmaf(-2.0f, s_, (WNV)) : INF;            \
        bool lt_ = (d_ < (BD)) || (d_ == (BD) && (C) < (BI));                \
        BD = lt_ ? d_ : (BD); BI = lt_ ? (C) : (BI); }
      UPD(bd0, bi0, da0, wna, ca, oka); UPD(bd0, bi0, db0, wnb, cbh, okb);
      UPD(bd1, bi1, da1, wna, ca, oka); UPD(bd1, bi1, db1, wnb, cbh, okb);
      UPD(bd2, bi2, da2, wna, ca, oka); UPD(bd2, bi2, db2, wnb, cbh, okb);
      UPD(bd3, bi3, da3, wna, ca, oka); UPD(bd3, bi3, db3, wnb, cbh, okb);
#undef UPD
    }
    // full-wave xor-reduce per flag (every lane ends with the winner)
#define RED(BD, BI)                                                          \
    { _Pragma("unroll")                                                      \
      for (int off = 1; off < 64; off <<= 1) {                               \
        float od = __shfl_xor(BD, off, 64);                                  \
        int   oi = __shfl_xor(BI, off, 64);                                  \
        bool tk = (od < (BD)) || (od == (BD) && oi < (BI));                  \
        BD = tk ? od : (BD); BI = tk ? oi : (BI);                            \
      } }
    RED(bd0, bi0); RED(bd1, bi1); RED(bd2, bi2); RED(bd3, bi3);
#undef RED
    // write winner rows (whole wave, coalesced 1KB per row)
    {
      const f32x4* s0 = (const f32x4*)(WL + (size_t)bi0 * DIM);
      f32x4* d0 = (f32x4*)(out + ((size_t)(L * N_TOK + tk0)) * DIM);
      d0[lane] = s0[lane];
    }
    if (mv > 1) {
      const f32x4* s1 = (const f32x4*)(WL + (size_t)bi1 * DIM);
      f32x4* d1 = (f32x4*)(out + ((size_t)(L * N_TOK + tk1)) * DIM);
      d1[lane] = s1[lane];
    }
    if (mv > 2) {
      const f32x4* s2 = (const f32x4*)(WL + (size_t)bi2 * DIM);
      f32x4* d2 = (f32x4*)(out + ((size_t)(L * N_TOK + tk2)) * DIM);
      d2[lane] = s2[lane];
    }
    if (mv > 3) {
      const f32x4* s3 = (const f32x4*)(WL + (size_t)bi3 * DIM);
      f32x4* d3 = (f32x4*)(out + ((size_t)(L * N_TOK + tk3)) * DIM);
      d3[lane] = s3[lane];
    }
  }
}

extern "C" void kernel_launch(void* const* d_in, const int* in_sizes, int n_in,
                              void* d_out, int out_size, void* d_ws, size_t ws_size,
                              hipStream_t stream) {
  const float* E  = (const float*)d_in[0];
  const float* w0 = (const float*)d_in[1];
  const float* w1 = (const float*)d_in[2];
  const float* w2 = (const float*)d_in[3];
  float* out = (float*)d_out;
  unsigned char* ws = (unsigned char*)d_ws;

  hipLaunchKernelGGL(prep_kernel,   dim3(NT),  dim3(256), 0, stream, w0, w1, w2, ws);
  hipLaunchKernelGGL(argmin_kernel, dim3(512), dim3(128), 0, stream, E, w0, w1, w2, out, ws);
  hipLaunchKernelGGL(refine_kernel, dim3(256), dim3(256), 0, stream, E, w0, w1, w2, out, ws);
}